// Round 1
// baseline (8937.851 us; speedup 1.0000x reference)
//
#include <hip/hip_runtime.h>
#include <hip/hip_cooperative_groups.h>

namespace cg = cooperative_groups;

#define H 4096
#define STEPS 100
#define IN_DIM_ 512
#define OUT_DIM_ 64
#define NWG 512
#define TPB 256
#define RGRP 32            // row groups (H / ROWS_PER_WG)
#define CGRP 16            // col groups (H / COLS_PER_WG)
#define ROWS_PER_WG 128
#define COLS_PER_WG 256
#define DECAY_F 0.95122942450071400910f  // float(exp(-1/20))

// workspace byte offsets (all 16-aligned)
#define OFF_IIN   0                       // STEPS*H f32      = 1,638,400 B
#define OFF_PART  1638400                 // 2*RGRP*H f32     = 1,048,576 B
#define OFF_VSUM  2686976                 // H f32            =    16,384 B
#define OFF_RED   2703360                 // 64*64 f32        =    16,384 B
#define OFF_DLY8  2719744                 // H*H u8           = 16,777,216 B
#define WS_NEED_PACK 19496960

__global__ __launch_bounds__(TPB, 2)
void triglial_kernel(const float* __restrict__ x,
                     const float* __restrict__ Wi,
                     const float* __restrict__ Wr,
                     const float* __restrict__ rw,
                     const float* __restrict__ rbias,
                     const int*   __restrict__ delays,
                     unsigned char* __restrict__ dly8,
                     int use_pack,
                     float* __restrict__ Iin,
                     float* __restrict__ partial,
                     float* __restrict__ vsum_g,
                     float* __restrict__ red_part,
                     float* __restrict__ out)
{
    cg::grid_group grid = cg::this_grid();
    const int wg  = blockIdx.x;
    const int tid = threadIdx.x;
    const int rg  = wg / CGRP;            // row-group id   [0,32)
    const int cgi = wg % CGRP;            // col-group id   [0,16)
    const int rowbase = rg * ROWS_PER_WG;
    const int jcol    = cgi * COLS_PER_WG + tid;

    // persistent per-wg LIF state for its 128 neurons (redundant across cgi,
    // bitwise-identical recompute -> only 1 grid barrier per step)
    __shared__ float    s_v[ROWS_PER_WG];
    __shared__ float    s_rate[ROWS_PER_WG];
    __shared__ float    s_gamma[ROWS_PER_WG];
    __shared__ float    s_vsum[ROWS_PER_WG];
    __shared__ unsigned s_hist[ROWS_PER_WG];
    __shared__ float    s_red[4][64];

    // ---------------- init ----------------
    if (tid < ROWS_PER_WG) {
        s_v[tid] = 0.f; s_rate[tid] = 0.f; s_gamma[tid] = 1.f;
        s_vsum[tid] = 0.f; s_hist[tid] = 0u;
    }
    // zero partial buffer 0 (step-0 recurrent input is zero: buf starts empty)
    for (int idx = wg * TPB + tid; idx < RGRP * H; idx += NWG * TPB)
        partial[idx] = 0.f;
    // pack (delay-1) into u8 once per launch (delays in [1,9] -> [0,8])
    if (use_pack) {
        const int total = H * H;
        for (int idx = wg * TPB + tid; idx < total; idx += NWG * TPB)
            dly8[idx] = (unsigned char)(delays[idx] - 1);
    }
    // precompute input currents for all steps: Iin[t][j] = x[t] . Wi[:,j]
    for (int idx = wg * TPB + tid; idx < STEPS * H; idx += NWG * TPB) {
        const int t = idx >> 12;
        const int j = idx & (H - 1);
        const float* xr = x + t * IN_DIM_;
        float s = 0.f;
        #pragma unroll 4
        for (int k = 0; k < IN_DIM_; ++k)
            s += xr[k] * Wi[k * H + j];
        Iin[idx] = s;
    }
    grid.sync();

    // ---------------- time loop: ONE grid barrier per step ----------------
    for (int t = 0; t < STEPS; ++t) {
        const float* pb = partial + (t & 1) * (RGRP * H);

        // LIF update for this wg's 128 neurons (mask==1 always: health >= 0.99^100 > 0.01)
        if (tid < ROWS_PER_WG) {
            const int n = rowbase + tid;
            float irec = 0.f;
            #pragma unroll
            for (int r = 0; r < RGRP; ++r)
                irec += pb[r * H + n];
            const float itot = (Iin[t * H + n] + irec) * s_gamma[tid];
            float v = s_v[tid] * DECAY_F + itot;
            const int spk = (v >= 1.0f) ? 1 : 0;
            v = spk ? 0.0f : v;
            s_v[tid] = v;
            s_vsum[tid] += v;                       // reference records post-reset v
            const float rate = 0.9f * s_rate[tid] + 0.1f * (float)spk;
            s_rate[tid] = rate;
            float g = s_gamma[tid] + 0.01f * (0.1f - rate);
            s_gamma[tid] = fminf(fmaxf(g, 0.5f), 2.0f);
            s_hist[tid] = ((s_hist[tid] << 1) | (unsigned)spk) & 1023u;
        }
        __syncthreads();

        // partial recurrent currents for step t+1:
        // partial[rg][j] = sum_{i in row block} W[i][j] * bit(hist[i], delay-1)
        if (t < STEPS - 1) {
            float s = 0.f;
            const size_t base = (size_t)rowbase * H + jcol;
            if (use_pack) {
                const float* wp = Wr + base;
                const unsigned char* dp = dly8 + base;
                #pragma unroll 8
                for (int ii = 0; ii < ROWS_PER_WG; ++ii) {
                    const unsigned h = s_hist[ii];
                    const float w = wp[(size_t)ii * H];
                    const unsigned d = dp[(size_t)ii * H];
                    s += ((h >> d) & 1u) ? w : 0.f;
                }
            } else {
                const float* wp = Wr + base;
                const int* dp = delays + base;
                #pragma unroll 8
                for (int ii = 0; ii < ROWS_PER_WG; ++ii) {
                    const unsigned h = s_hist[ii];
                    const float w = wp[(size_t)ii * H];
                    const unsigned d = (unsigned)(dp[(size_t)ii * H] - 1);
                    s += ((h >> d) & 1u) ? w : 0.f;
                }
            }
            partial[((t + 1) & 1) * (RGRP * H) + rg * H + jcol] = s;
        }
        grid.sync();
    }

    // ---------------- readout: out = (vsum/STEPS) @ rw + rbias ----------------
    if (cgi == 0 && tid < ROWS_PER_WG)
        vsum_g[rowbase + tid] = s_vsum[tid];
    grid.sync();

    if (wg < 64) {                          // wg handles j in [wg*64, wg*64+64)
        const int o  = tid & 63;
        const int jl = tid >> 6;
        float s = 0.f;
        for (int j = wg * 64 + jl; j < wg * 64 + 64; j += 4)
            s += (vsum_g[j] * (1.0f / (float)STEPS)) * rw[j * OUT_DIM_ + o];
        s_red[jl][o] = s;
        __syncthreads();
        if (tid < 64)
            red_part[wg * 64 + tid] =
                s_red[0][tid] + s_red[1][tid] + s_red[2][tid] + s_red[3][tid];
    }
    grid.sync();

    if (wg == 0 && tid < OUT_DIM_) {
        float s = rbias[tid];
        #pragma unroll 8
        for (int w = 0; w < 64; ++w)
            s += red_part[w * 64 + tid];
        out[tid] = s;
    }
}

extern "C" void kernel_launch(void* const* d_in, const int* in_sizes, int n_in,
                              void* d_out, int out_size, void* d_ws, size_t ws_size,
                              hipStream_t stream) {
    const float* x      = (const float*)d_in[0];
    const float* Wi     = (const float*)d_in[1];
    const float* Wr     = (const float*)d_in[2];
    const float* rw     = (const float*)d_in[3];
    const float* rb     = (const float*)d_in[4];
    const int*   delays = (const int*)d_in[5];
    float* out = (float*)d_out;

    char* ws = (char*)d_ws;
    float* Iin      = (float*)(ws + OFF_IIN);
    float* partial  = (float*)(ws + OFF_PART);
    float* vsum_g   = (float*)(ws + OFF_VSUM);
    float* red_part = (float*)(ws + OFF_RED);
    unsigned char* dly8 = (unsigned char*)(ws + OFF_DLY8);
    int use_pack = (ws_size >= (size_t)WS_NEED_PACK) ? 1 : 0;

    void* args[] = { (void*)&x, (void*)&Wi, (void*)&Wr, (void*)&rw, (void*)&rb,
                     (void*)&delays, (void*)&dly8, (void*)&use_pack,
                     (void*)&Iin, (void*)&partial, (void*)&vsum_g, (void*)&red_part,
                     (void*)&out };
    hipLaunchCooperativeKernel((void*)triglial_kernel, dim3(NWG), dim3(TPB),
                               args, 0, stream);
}

// Round 4
// 8077.982 us; speedup vs baseline: 1.1064x; 1.1064x over previous
//
#include <hip/hip_runtime.h>
#include <hip/hip_cooperative_groups.h>

namespace cg = cooperative_groups;

#define H 4096
#define STEPS 100
#define IN_DIM_ 512
#define OUT_DIM_ 64
#define NWG 512            // PROVEN cooperative config (round 1): 512 wgs x 256 thr
#define TPB 256
#define RGRP 32            // row groups  (H / ROWS_PER_WG)
#define CGRP 16            // col groups  (H / COLS_PER_WG)
#define ROWS_PER_WG 128
#define COLS_PER_WG 256
#define NSLOT 10
#define DECAY_F 0.95122942450071400910f  // float(exp(-1/20))

// workspace byte offsets (16-aligned) — identical layout to round 1
#define OFF_IIN   0                        // STEPS*H f32      = 1,638,400 B
#define OFF_PART  1638400                  // 2*RGRP*H f32     = 1,048,576 B
#define OFF_VSUM  2686976                  // H f32            =    16,384 B
#define OFF_RED   2703360                  // 64*64 f32        =    16,384 B
#define OFF_DLY8  2719744                  // H*H u8           = 16,777,216 B
#define WS_NEED_PACK 19496960

__global__ __launch_bounds__(TPB, 2)
void triglial_kernel(const float* __restrict__ x,
                     const float* __restrict__ Wi,
                     const float* __restrict__ Wr,
                     const float* __restrict__ rw,
                     const float* __restrict__ rbias,
                     const int*   __restrict__ delays,
                     unsigned char* __restrict__ dly8,
                     int use_pack,
                     float* __restrict__ Iin,
                     float* __restrict__ partial,
                     float* __restrict__ vsum_g,
                     float* __restrict__ red_part,
                     float* __restrict__ out)
{
    cg::grid_group grid = cg::this_grid();
    const int wg   = blockIdx.x;
    const int tid  = threadIdx.x;
    const int rg   = wg >> 4;              // row-group id [0,32)
    const int cgi  = wg & 15;              // col-group id [0,16)
    const int rowbase = rg * ROWS_PER_WG;  // 128 presynaptic rows owned
    const int colbase = cgi * COLS_PER_WG; // 256 output cols owned
    const int wave = tid >> 6, lane = tid & 63;
    const int mycol = colbase + tid;       // exclusive column of this thread

    // per-wave future-current accumulator: acc[slot][col-within-wave]
    __shared__ float s_acc[4][NSLOT][64];
    __shared__ float s_part[2][ROWS_PER_WG];
    __shared__ float s_v[ROWS_PER_WG], s_rate[ROWS_PER_WG],
                     s_gamma[ROWS_PER_WG], s_vsum[ROWS_PER_WG];
    __shared__ unsigned long long s_spk[2];
    __shared__ float s_red[4][64];

    // ---------------- init ----------------
    if (tid < ROWS_PER_WG) {
        s_v[tid]=0.f; s_rate[tid]=0.f; s_gamma[tid]=1.f; s_vsum[tid]=0.f;
    }
    for (int i = tid; i < 4*NSLOT*64; i += TPB) ((float*)s_acc)[i] = 0.f;
    // zero both partial buffers (step-0 recurrent input is zero)
    for (int idx = wg*TPB + tid; idx < 2*RGRP*H; idx += NWG*TPB) partial[idx] = 0.f;
    // pack (delay-1) into u8 once per launch (delays in [1,9] -> [0,8])
    if (use_pack) {
        for (int idx = wg*TPB + tid; idx < H*H; idx += NWG*TPB)
            dly8[idx] = (unsigned char)(delays[idx] - 1);
    }
    // precompute input currents: Iin[t][j] = x[t] . Wi[:,j]
    for (int idx = wg*TPB + tid; idx < STEPS*H; idx += NWG*TPB) {
        const int t = idx >> 12;
        const int j = idx & (H - 1);
        const float* xr = x + t * IN_DIM_;
        float s = 0.f;
        #pragma unroll 4
        for (int k = 0; k < IN_DIM_; ++k) s += xr[k] * Wi[k * H + j];
        Iin[idx] = s;
    }
    grid.sync();

    // ---------------- time loop: one grid barrier per step ----------------
    for (int t = 0; t < STEPS; ++t) {
        // ---- phase A: reduce partials + LIF for this wg's 128 neurons ----
        {   // 32-way partial reduction: 2 slices x 128 neurons
            const int n = tid & 127, p = tid >> 7;
            const float* pb = partial + (t & 1) * (RGRP * H);
            const int gn = rowbase + n;
            float s = 0.f;
            #pragma unroll
            for (int k = 0; k < 16; ++k) s += pb[(p*16 + k) * H + gn];
            s_part[p][n] = s;
        }
        __syncthreads();
        if (tid < ROWS_PER_WG) {
            const float irec = s_part[0][tid] + s_part[1][tid];
            // microglia mask == 1 always: health >= 0.99^99 ~= 0.37 > 0.01
            const float itot = (Iin[t*H + rowbase + tid] + irec) * s_gamma[tid];
            float v = s_v[tid] * DECAY_F + itot;
            const int spk = (v >= 1.0f) ? 1 : 0;
            v = spk ? 0.0f : v;
            s_v[tid] = v;
            s_vsum[tid] += v;                       // reference records post-reset v
            const float rate = 0.9f * s_rate[tid] + 0.1f * (float)spk;
            s_rate[tid] = rate;
            float g = s_gamma[tid] + 0.01f * (0.1f - rate);
            s_gamma[tid] = fminf(fmaxf(g, 0.5f), 2.0f);
            const unsigned long long bal = __ballot(spk);
            if ((tid & 63) == 0) s_spk[tid >> 6] = bal;
        }
        __syncthreads();

        // ---- phase B: push this step's spikes into future slots; export t+1 ----
        if (t < STEPS - 1) {
            const int tmod = t % 10;
            #pragma unroll
            for (int wrd = 0; wrd < 2; ++wrd) {
                unsigned long long m = s_spk[wrd];
                while (m) {
                    const int ii = __ffsll(m) - 1; m &= m - 1;
                    const size_t base =
                        (size_t)(rowbase + (wrd << 6) + ii) * H + mycol;
                    const float w = Wr[base];
                    const int d8 = use_pack ? (int)dly8[base] : (delays[base] - 1);
                    int slot = tmod + 1 + d8;        // target (t+1+d8) mod 10
                    slot -= (slot >= 10) ? 10 : 0;
                    s_acc[wave][slot][lane] += w;    // lane owns this col: race-free
                }
            }
            int es = tmod + 1; es -= (es >= 10) ? 10 : 0;
            const float ex = s_acc[wave][es][lane];  // all adds for step t+1 done
            s_acc[wave][es][lane] = 0.f;             // recycle for step t+11
            partial[((t+1) & 1) * (RGRP*H) + rg*H + mycol] = ex;
        }
        grid.sync();
    }

    // ---------------- readout: out = (vsum/STEPS) @ rw + rbias ----------------
    if (cgi == 0 && tid < ROWS_PER_WG) vsum_g[rowbase + tid] = s_vsum[tid];
    grid.sync();

    if (wg < 64) {                          // wg handles j in [wg*64, wg*64+64)
        const int o  = tid & 63;
        const int jl = tid >> 6;
        float s = 0.f;
        for (int j = wg*64 + jl; j < wg*64 + 64; j += 4)
            s += (vsum_g[j] * (1.0f / (float)STEPS)) * rw[j * OUT_DIM_ + o];
        s_red[jl][o] = s;
        __syncthreads();
        if (tid < 64)
            red_part[wg*64 + tid] =
                s_red[0][tid] + s_red[1][tid] + s_red[2][tid] + s_red[3][tid];
    }
    grid.sync();

    if (wg == 0 && tid < OUT_DIM_) {
        float s = rbias[tid];
        #pragma unroll 8
        for (int w = 0; w < 64; ++w) s += red_part[w * 64 + tid];
        out[tid] = s;
    }
}

extern "C" void kernel_launch(void* const* d_in, const int* in_sizes, int n_in,
                              void* d_out, int out_size, void* d_ws, size_t ws_size,
                              hipStream_t stream) {
    const float* x      = (const float*)d_in[0];
    const float* Wi     = (const float*)d_in[1];
    const float* Wr     = (const float*)d_in[2];
    const float* rw     = (const float*)d_in[3];
    const float* rb     = (const float*)d_in[4];
    const int*   delays = (const int*)d_in[5];
    float* out = (float*)d_out;

    char* ws = (char*)d_ws;
    float* Iin      = (float*)(ws + OFF_IIN);
    float* partial  = (float*)(ws + OFF_PART);
    float* vsum_g   = (float*)(ws + OFF_VSUM);
    float* red_part = (float*)(ws + OFF_RED);
    unsigned char* dly8 = (unsigned char*)(ws + OFF_DLY8);
    int use_pack = (ws_size >= (size_t)WS_NEED_PACK) ? 1 : 0;

    void* args[] = { (void*)&x, (void*)&Wi, (void*)&Wr, (void*)&rw, (void*)&rb,
                     (void*)&delays, (void*)&dly8, (void*)&use_pack,
                     (void*)&Iin, (void*)&partial, (void*)&vsum_g, (void*)&red_part,
                     (void*)&out };
    hipLaunchCooperativeKernel((void*)triglial_kernel, dim3(NWG), dim3(TPB),
                               args, 0, stream);
}

// Round 5
// 3751.148 us; speedup vs baseline: 2.3827x; 2.1535x over previous
//
#include <hip/hip_runtime.h>

#define H 4096
#define STEPS 100
#define IN_DIM_ 512
#define OUT_DIM_ 64
#define NWG 512            // PROVEN cooperative config: 512 wgs x 256 thr
#define TPB 256
#define RGRP 32            // row groups  (H / ROWS_PER_WG)
#define CGRP 16            // col groups  (H / COLS_PER_WG)
#define ROWS_PER_WG 128
#define COLS_PER_WG 256
#define NSLOT 10
#define DECAY_F 0.95122942450071400910f  // float(exp(-1/20))

// ---- workspace layout (bytes) ----
// [0,4096): sync counters, zeroed via hipMemsetAsync each launch
#define OFF_BAR   0
#define OFF_IIN   4096                     // STEPS*H f32      = 1,638,400 B
#define OFF_PART  1642496                  // 2*RGRP*H f32     = 1,048,576 B
#define OFF_VSUM  2691072                  // H f32            =    16,384 B
#define OFF_RED   2707456                  // 64*64 f32        =    16,384 B
#define OFF_DLY8  2723840                  // H*H u8           = 16,777,216 B
#define WS_NEED_PACK 19501056

// counter indices (each on its own 64B line)
#define BAR_FWD(c)  ((c) * 16)             // c in [0,16): producers of col-group c
#define BAR_BWD(c)  ((16 + (c)) * 16)      // consumers of col-group c's buffer
#define BAR_GRP(g)  ((32 + (g)) * 16)      // full-barrier tree: 16 groups of 32 wgs
#define BAR_GCNT    (48 * 16)
#define BAR_FLAG    (49 * 16)

__device__ __forceinline__ void wait_ge(unsigned* p, unsigned tgt) {
    while (__hip_atomic_load(p, __ATOMIC_RELAXED, __HIP_MEMORY_SCOPE_AGENT) < tgt)
        __builtin_amdgcn_s_sleep(1);
}

// hierarchical full-grid barrier (monotonic generations, no resets)
__device__ __forceinline__ void full_barrier(unsigned* bar, int wg, unsigned gen, int tid) {
    __syncthreads();                       // drains this block's memory ops
    if (tid == 0) {
        __threadfence();                   // release
        unsigned o = atomicAdd(bar + BAR_GRP(wg >> 5), 1u);
        if (o == gen * 32u - 1u) {         // last of my 32-wg group this gen
            unsigned g = atomicAdd(bar + BAR_GCNT, 1u);
            if (g == gen * 16u - 1u)       // last group
                __hip_atomic_store(bar + BAR_FLAG, gen, __ATOMIC_RELAXED,
                                   __HIP_MEMORY_SCOPE_AGENT);
        }
        wait_ge(bar + BAR_FLAG, gen);
        __threadfence();                   // acquire
    }
    __syncthreads();
}

__global__ __launch_bounds__(TPB, 2)
void triglial_kernel(const float* __restrict__ x,
                     const float* __restrict__ Wi,
                     const float* __restrict__ Wr,
                     const float* __restrict__ rw,
                     const float* __restrict__ rbias,
                     const int*   __restrict__ delays,
                     unsigned char* __restrict__ dly8,
                     int use_pack,
                     unsigned* __restrict__ bar,
                     float* __restrict__ Iin,
                     float* __restrict__ partial,
                     float* __restrict__ vsum_g,
                     float* __restrict__ red_part,
                     float* __restrict__ out)
{
    const int wg   = blockIdx.x;
    const int tid  = threadIdx.x;
    const int rg   = wg >> 4;              // row-group id [0,32)
    const int cgi  = wg & 15;              // col-group id [0,16)
    const int rowbase = rg * ROWS_PER_WG;  // 128 presynaptic rows owned
    const int colbase = cgi * COLS_PER_WG; // 256 output cols owned
    const int wave = tid >> 6, lane = tid & 63;
    const int mycol = colbase + tid;       // exclusive column of this thread

    __shared__ float s_acc[4][NSLOT][64];  // per-wave future-current accumulator
    __shared__ float s_part[2][ROWS_PER_WG];
    __shared__ float s_v[ROWS_PER_WG], s_rate[ROWS_PER_WG],
                     s_gamma[ROWS_PER_WG], s_vsum[ROWS_PER_WG];
    __shared__ unsigned long long s_spk[2];
    __shared__ float s_red[4][64];

    // ---------------- init ----------------
    if (tid < ROWS_PER_WG) {
        s_v[tid]=0.f; s_rate[tid]=0.f; s_gamma[tid]=1.f; s_vsum[tid]=0.f;
    }
    for (int i = tid; i < 4*NSLOT*64; i += TPB) ((float*)s_acc)[i] = 0.f;
    for (int idx = wg*TPB + tid; idx < 2*RGRP*H; idx += NWG*TPB) partial[idx] = 0.f;
    if (use_pack) {
        for (int idx = wg*TPB + tid; idx < H*H; idx += NWG*TPB)
            dly8[idx] = (unsigned char)(delays[idx] - 1);
    }
    for (int idx = wg*TPB + tid; idx < STEPS*H; idx += NWG*TPB) {
        const int t = idx >> 12;
        const int j = idx & (H - 1);
        const float* xr = x + t * IN_DIM_;
        float s = 0.f;
        #pragma unroll 4
        for (int k = 0; k < IN_DIM_; ++k) s += xr[k] * Wi[k * H + j];
        Iin[idx] = s;
    }
    full_barrier(bar, wg, 1u, tid);

    // ------------- time loop: partitioned dataflow sync, no grid barrier -------------
    for (int t = 0; t < STEPS; ++t) {
        // wait: my 32 producers exported step t's data; my buffer's 32 readers done
        if (tid == 0) {
            wait_ge(bar + BAR_FWD(rg >> 1), 32u * (unsigned)t);
            wait_ge(bar + BAR_BWD(cgi),     32u * (unsigned)t);
            __threadfence();               // acquire
        }
        __syncthreads();

        // ---- phase A: reduce partials (2 slices x 128 neurons) ----
        {
            const int n = tid & 127, p = tid >> 7;
            const float* pb = partial + (t & 1) * (RGRP * H);
            const int gn = rowbase + n;
            float s = 0.f;
            #pragma unroll
            for (int k = 0; k < 16; ++k) s += pb[(p*16 + k) * H + gn];
            s_part[p][n] = s;
        }
        __syncthreads();                   // drains phase-A loads (vmcnt 0 at barrier)
        if (tid == 0) atomicAdd(bar + BAR_BWD(rg >> 1), 1u);  // my reads are done

        // ---- LIF for this wg's 128 neurons (microglia mask==1: 0.99^99 > 0.01) ----
        if (tid < ROWS_PER_WG) {
            const float irec = s_part[0][tid] + s_part[1][tid];
            const float itot = (Iin[t*H + rowbase + tid] + irec) * s_gamma[tid];
            float v = s_v[tid] * DECAY_F + itot;
            const int spk = (v >= 1.0f) ? 1 : 0;
            v = spk ? 0.0f : v;
            s_v[tid] = v;
            s_vsum[tid] += v;              // reference records post-reset v
            const float rate = 0.9f * s_rate[tid] + 0.1f * (float)spk;
            s_rate[tid] = rate;
            float g = s_gamma[tid] + 0.01f * (0.1f - rate);
            s_gamma[tid] = fminf(fmaxf(g, 0.5f), 2.0f);
            const unsigned long long bal = __ballot(spk);
            if ((tid & 63) == 0) s_spk[tid >> 6] = bal;
        }
        __syncthreads();

        // ---- phase B: push spikes into future slots (8-deep load batching) ----
        if (t < STEPS - 1) {
            const int tmod = t % 10;
            unsigned long long m0 = s_spk[0], m1 = s_spk[1];
            while (m0 | m1) {
                float wv[8]; int dv[8];
                int cnt = 0;
                #pragma unroll
                for (int b = 0; b < 8; ++b) {
                    if (m0 | m1) {
                        int ii;
                        if (m0) { ii = __ffsll(m0) - 1; m0 &= m0 - 1; }
                        else    { ii = 64 + __ffsll(m1) - 1; m1 &= m1 - 1; }
                        const size_t base = (size_t)(rowbase + ii) * H + mycol;
                        wv[b] = Wr[base];                       // independent loads,
                        dv[b] = use_pack ? (int)dly8[base]      // batched before use
                                         : (delays[base] - 1);
                        ++cnt;
                    }
                }
                #pragma unroll
                for (int b = 0; b < 8; ++b) {
                    if (b < cnt) {
                        int slot = tmod + 1 + dv[b];            // (t+1+d) mod 10
                        slot -= (slot >= 10) ? 10 : 0;
                        s_acc[wave][slot][lane] += wv[b];       // lane owns col
                    }
                }
            }
            int es = tmod + 1; es -= (es >= 10) ? 10 : 0;
            const float ex = s_acc[wave][es][lane];             // step-t+1 current
            s_acc[wave][es][lane] = 0.f;                        // recycle for t+11
            partial[((t+1) & 1) * (RGRP*H) + rg*H + mycol] = ex;
        }
        __syncthreads();                   // drain export stores
        if (tid == 0 && t < STEPS - 1) {
            __threadfence();               // release export
            atomicAdd(bar + BAR_FWD(cgi), 1u);
        }
    }

    // ---------------- readout: out = (vsum/STEPS) @ rw + rbias ----------------
    if (cgi == 0 && tid < ROWS_PER_WG) vsum_g[rowbase + tid] = s_vsum[tid];
    full_barrier(bar, wg, 2u, tid);

    if (wg < 64) {                         // wg handles j in [wg*64, wg*64+64)
        const int o  = tid & 63;
        const int jl = tid >> 6;
        float s = 0.f;
        for (int j = wg*64 + jl; j < wg*64 + 64; j += 4)
            s += (vsum_g[j] * (1.0f / (float)STEPS)) * rw[j * OUT_DIM_ + o];
        s_red[jl][o] = s;
        __syncthreads();
        if (tid < 64)
            red_part[wg*64 + tid] =
                s_red[0][tid] + s_red[1][tid] + s_red[2][tid] + s_red[3][tid];
    }
    full_barrier(bar, wg, 3u, tid);

    if (wg == 0 && tid < OUT_DIM_) {
        float s = rbias[tid];
        #pragma unroll 8
        for (int w = 0; w < 64; ++w) s += red_part[w * 64 + tid];
        out[tid] = s;
    }
}

extern "C" void kernel_launch(void* const* d_in, const int* in_sizes, int n_in,
                              void* d_out, int out_size, void* d_ws, size_t ws_size,
                              hipStream_t stream) {
    const float* x      = (const float*)d_in[0];
    const float* Wi     = (const float*)d_in[1];
    const float* Wr     = (const float*)d_in[2];
    const float* rw     = (const float*)d_in[3];
    const float* rb     = (const float*)d_in[4];
    const int*   delays = (const int*)d_in[5];
    float* out = (float*)d_out;

    char* ws = (char*)d_ws;
    unsigned* bar   = (unsigned*)(ws + OFF_BAR);
    float* Iin      = (float*)(ws + OFF_IIN);
    float* partial  = (float*)(ws + OFF_PART);
    float* vsum_g   = (float*)(ws + OFF_VSUM);
    float* red_part = (float*)(ws + OFF_RED);
    unsigned char* dly8 = (unsigned char*)(ws + OFF_DLY8);
    int use_pack = (ws_size >= (size_t)WS_NEED_PACK) ? 1 : 0;

    // zero the sync counters (harness poisons ws with 0xAA before every launch)
    hipMemsetAsync(ws + OFF_BAR, 0, 4096, stream);

    void* args[] = { (void*)&x, (void*)&Wi, (void*)&Wr, (void*)&rw, (void*)&rb,
                     (void*)&delays, (void*)&dly8, (void*)&use_pack, (void*)&bar,
                     (void*)&Iin, (void*)&partial, (void*)&vsum_g, (void*)&red_part,
                     (void*)&out };
    hipLaunchCooperativeKernel((void*)triglial_kernel, dim3(NWG), dim3(TPB),
                               args, 0, stream);
}

// Round 6
// 3437.037 us; speedup vs baseline: 2.6005x; 1.0914x over previous
//
#include <hip/hip_runtime.h>

#define H 4096
#define STEPS 100
#define IN_DIM_ 512
#define OUT_DIM_ 64
#define NWG 512            // PROVEN cooperative config: 512 wgs x 256 thr
#define TPB 256
#define RGRP 32            // row groups  (H / ROWS_PER_WG)
#define CGRP 16            // col groups  (H / COLS_PER_WG)
#define ROWS_PER_WG 128
#define COLS_PER_WG 256
#define NSLOT 10
#define NBUF 4             // partial double->quad buffer: bwd wait is slack now
#define DECAY_F 0.95122942450071400910f  // float(exp(-1/20))

// ---- workspace layout (bytes) ----
// [0,8192): sync stamps/counters, zeroed via hipMemsetAsync each launch
#define OFF_BAR   0
#define OFF_IIN   8192                     // STEPS*H f32      = 1,638,400 B
#define OFF_PART  1646592                  // NBUF*RGRP*H f32  = 2,097,152 B
#define OFF_VSUM  3743744                  // H f32            =    16,384 B
#define OFF_RED   3760128                  // 64*64 f32        =    16,384 B
#define OFF_DLY8  3776512                  // H*H u8           = 16,777,216 B
#define WS_NEED_PACK 20553728

// word indices into bar[]
#define STAMP_FWD(c)  ((c) * 32)           // [c][p]: producer (p,c) export stamp
#define STAMP_BWD(c)  (512 + (c) * 32)     // [c][q]: reader q of col-group c's buf
#define BAR_GRP(g)    (1024 + (g) * 16)    // full-barrier tree: 16 groups of 32 wgs
#define BAR_GCNT      1280
#define BAR_FLAG      1296

__device__ __forceinline__ void wait_ge(unsigned* p, unsigned tgt) {
    while (__hip_atomic_load(p, __ATOMIC_RELAXED, __HIP_MEMORY_SCOPE_AGENT) < tgt)
        __builtin_amdgcn_s_sleep(1);
}

// hierarchical full-grid barrier (monotonic generations, no resets) — init/readout only
__device__ __forceinline__ void full_barrier(unsigned* bar, int wg, unsigned gen, int tid) {
    __syncthreads();
    if (tid == 0) {
        __threadfence();                   // release
        unsigned o = atomicAdd(bar + BAR_GRP(wg >> 5), 1u);
        if (o == gen * 32u - 1u) {
            unsigned g = atomicAdd(bar + BAR_GCNT, 1u);
            if (g == gen * 16u - 1u)
                __hip_atomic_store(bar + BAR_FLAG, gen, __ATOMIC_RELAXED,
                                   __HIP_MEMORY_SCOPE_AGENT);
        }
        wait_ge(bar + BAR_FLAG, gen);
        __threadfence();                   // acquire
    }
    __syncthreads();
}

__global__ __launch_bounds__(TPB, 2)
void triglial_kernel(const float* __restrict__ x,
                     const float* __restrict__ Wi,
                     const float* __restrict__ Wr,
                     const float* __restrict__ rw,
                     const float* __restrict__ rbias,
                     const int*   __restrict__ delays,
                     unsigned char* __restrict__ dly8,
                     int use_pack,
                     unsigned* __restrict__ bar,
                     float* __restrict__ Iin,
                     float* __restrict__ partial,
                     float* __restrict__ vsum_g,
                     float* __restrict__ red_part,
                     float* __restrict__ out)
{
    const int wg   = blockIdx.x;
    const int tid  = threadIdx.x;
    const int rg   = wg >> 4;              // row-group id [0,32)
    const int cgi  = wg & 15;              // col-group id [0,16)
    const int rowbase = rg * ROWS_PER_WG;  // 128 presynaptic rows owned
    const int colbase = cgi * COLS_PER_WG; // 256 output cols owned
    const int wave = tid >> 6, lane = tid & 63;
    const int mycol = colbase + tid;       // exclusive column of this thread

    __shared__ float s_acc[4][NSLOT][64];  // per-wave future-current accumulator
    __shared__ float s_part[2][ROWS_PER_WG];
    __shared__ float s_v[ROWS_PER_WG], s_rate[ROWS_PER_WG],
                     s_gamma[ROWS_PER_WG], s_vsum[ROWS_PER_WG];
    __shared__ unsigned long long s_spk[2];
    __shared__ float s_red[4][64];

    // ---------------- init ----------------
    if (tid < ROWS_PER_WG) {
        s_v[tid]=0.f; s_rate[tid]=0.f; s_gamma[tid]=1.f; s_vsum[tid]=0.f;
    }
    for (int i = tid; i < 4*NSLOT*64; i += TPB) ((float*)s_acc)[i] = 0.f;
    for (int idx = wg*TPB + tid; idx < NBUF*RGRP*H; idx += NWG*TPB) partial[idx] = 0.f;
    if (use_pack) {
        for (int idx = wg*TPB + tid; idx < H*H; idx += NWG*TPB)
            dly8[idx] = (unsigned char)(delays[idx] - 1);
    }
    for (int idx = wg*TPB + tid; idx < STEPS*H; idx += NWG*TPB) {
        const int t = idx >> 12;
        const int j = idx & (H - 1);
        const float* xr = x + t * IN_DIM_;
        float s = 0.f;
        #pragma unroll 4
        for (int k = 0; k < IN_DIM_; ++k) s += xr[k] * Wi[k * H + j];
        Iin[idx] = s;
    }
    full_barrier(bar, wg, 1u, tid);

    // ------- time loop: stamp-based dataflow sync (parallel store + 64-lane poll) -------
    for (int t = 0; t < STEPS; ++t) {
        // wait: 32 producers of my cols exported step t (fwd >= t);
        //       32 readers of my export buffer are >= t-2 steps in (bwd, slack via NBUF=4)
        if (tid < 64) {
            unsigned* addr;
            unsigned tgt;
            if (lane < 32) { addr = bar + STAMP_FWD(rg >> 1) + lane; tgt = (unsigned)t; }
            else { addr = bar + STAMP_BWD(cgi) + (lane - 32);
                   tgt = (t >= 2) ? (unsigned)(t - 2) : 0u; }
            for (;;) {
                unsigned v = __hip_atomic_load(addr, __ATOMIC_RELAXED,
                                               __HIP_MEMORY_SCOPE_AGENT);
                if (__all((int)(v >= tgt))) break;
                __builtin_amdgcn_s_sleep(2);
            }
            if (tid == 0) __threadfence();  // acquire
        }
        __syncthreads();

        // ---- phase A: reduce partials (2 slices x 128 neurons) ----
        {
            const int n = tid & 127, p = tid >> 7;
            const float* pb = partial + (t & (NBUF-1)) * (RGRP * H);
            const int gn = rowbase + n;
            float s = 0.f;
            #pragma unroll
            for (int k = 0; k < 16; ++k) s += pb[(p*16 + k) * H + gn];
            s_part[p][n] = s;
        }
        __syncthreads();                   // phase-A loads consumed
        if (tid == 0)                      // signal: my read of this buffer is done
            __hip_atomic_store(bar + STAMP_BWD(rg >> 1) + ((rg & 1) * 16 + cgi),
                               (unsigned)(t + 1), __ATOMIC_RELAXED,
                               __HIP_MEMORY_SCOPE_AGENT);

        // ---- LIF for this wg's 128 neurons (microglia mask==1: 0.99^99 > 0.01) ----
        if (tid < ROWS_PER_WG) {
            const float irec = s_part[0][tid] + s_part[1][tid];
            const float itot = (Iin[t*H + rowbase + tid] + irec) * s_gamma[tid];
            float v = s_v[tid] * DECAY_F + itot;
            const int spk = (v >= 1.0f) ? 1 : 0;
            v = spk ? 0.0f : v;
            s_v[tid] = v;
            s_vsum[tid] += v;              // reference records post-reset v
            const float rate = 0.9f * s_rate[tid] + 0.1f * (float)spk;
            s_rate[tid] = rate;
            float g = s_gamma[tid] + 0.01f * (0.1f - rate);
            s_gamma[tid] = fminf(fmaxf(g, 0.5f), 2.0f);
            const unsigned long long bal = __ballot(spk);
            if ((tid & 63) == 0) s_spk[tid >> 6] = bal;
        }
        __syncthreads();

        // ---- phase B: push spikes into future slots (16-deep load batching) ----
        if (t < STEPS - 1) {
            const int tmod = t % 10;
            unsigned long long m0 = s_spk[0], m1 = s_spk[1];
            while (m0 | m1) {
                float wv[16]; int dv[16];
                int cnt = 0;
                #pragma unroll
                for (int b = 0; b < 16; ++b) {
                    if (m0 | m1) {
                        int ii;
                        if (m0) { ii = __ffsll(m0) - 1; m0 &= m0 - 1; }
                        else    { ii = 64 + __ffsll(m1) - 1; m1 &= m1 - 1; }
                        const size_t base = (size_t)(rowbase + ii) * H + mycol;
                        wv[b] = Wr[base];                  // batched independent loads
                        dv[b] = use_pack ? (int)dly8[base] : (delays[base] - 1);
                        ++cnt;
                    }
                }
                #pragma unroll
                for (int b = 0; b < 16; ++b) {
                    if (b < cnt) {
                        int slot = tmod + 1 + dv[b];       // (t+1+d) mod 10
                        slot -= (slot >= 10) ? 10 : 0;
                        s_acc[wave][slot][lane] += wv[b];  // lane owns col: race-free
                    }
                }
            }
            int es = tmod + 1; es -= (es >= 10) ? 10 : 0;
            const float ex = s_acc[wave][es][lane];        // step-t+1 current complete
            s_acc[wave][es][lane] = 0.f;                   // recycle for t+11
            partial[((t+1) & (NBUF-1)) * (RGRP*H) + rg*H + mycol] = ex;
        }
        __syncthreads();                   // export stores drained (vmcnt0 at barrier)
        if (tid == 0 && t < STEPS - 1) {
            __threadfence();               // release export to agent scope
            __hip_atomic_store(bar + STAMP_FWD(cgi) + rg, (unsigned)(t + 1),
                               __ATOMIC_RELAXED, __HIP_MEMORY_SCOPE_AGENT);
        }
    }

    // ---------------- readout: out = (vsum/STEPS) @ rw + rbias ----------------
    if (cgi == 0 && tid < ROWS_PER_WG) vsum_g[rowbase + tid] = s_vsum[tid];
    full_barrier(bar, wg, 2u, tid);

    if (wg < 64) {                         // wg handles j in [wg*64, wg*64+64)
        const int o  = tid & 63;
        const int jl = tid >> 6;
        float s = 0.f;
        for (int j = wg*64 + jl; j < wg*64 + 64; j += 4)
            s += (vsum_g[j] * (1.0f / (float)STEPS)) * rw[j * OUT_DIM_ + o];
        s_red[jl][o] = s;
        __syncthreads();
        if (tid < 64)
            red_part[wg*64 + tid] =
                s_red[0][tid] + s_red[1][tid] + s_red[2][tid] + s_red[3][tid];
    }
    full_barrier(bar, wg, 3u, tid);

    if (wg == 0 && tid < OUT_DIM_) {
        float s = rbias[tid];
        #pragma unroll 8
        for (int w = 0; w < 64; ++w) s += red_part[w * 64 + tid];
        out[tid] = s;
    }
}

extern "C" void kernel_launch(void* const* d_in, const int* in_sizes, int n_in,
                              void* d_out, int out_size, void* d_ws, size_t ws_size,
                              hipStream_t stream) {
    const float* x      = (const float*)d_in[0];
    const float* Wi     = (const float*)d_in[1];
    const float* Wr     = (const float*)d_in[2];
    const float* rw     = (const float*)d_in[3];
    const float* rb     = (const float*)d_in[4];
    const int*   delays = (const int*)d_in[5];
    float* out = (float*)d_out;

    char* ws = (char*)d_ws;
    unsigned* bar   = (unsigned*)(ws + OFF_BAR);
    float* Iin      = (float*)(ws + OFF_IIN);
    float* partial  = (float*)(ws + OFF_PART);
    float* vsum_g   = (float*)(ws + OFF_VSUM);
    float* red_part = (float*)(ws + OFF_RED);
    unsigned char* dly8 = (unsigned char*)(ws + OFF_DLY8);
    int use_pack = (ws_size >= (size_t)WS_NEED_PACK) ? 1 : 0;

    // zero the sync stamps (harness poisons ws with 0xAA before every launch)
    hipMemsetAsync(ws + OFF_BAR, 0, 8192, stream);

    void* args[] = { (void*)&x, (void*)&Wi, (void*)&Wr, (void*)&rw, (void*)&rb,
                     (void*)&delays, (void*)&dly8, (void*)&use_pack, (void*)&bar,
                     (void*)&Iin, (void*)&partial, (void*)&vsum_g, (void*)&red_part,
                     (void*)&out };
    hipLaunchCooperativeKernel((void*)triglial_kernel, dim3(NWG), dim3(TPB),
                               args, 0, stream);
}

// Round 9
// 1489.904 us; speedup vs baseline: 5.9989x; 2.3069x over previous
//
#include <hip/hip_runtime.h>

#define H 4096
#define STEPS 100
#define IN_DIM_ 512
#define OUT_DIM_ 64
#define NWG 512            // PROVEN cooperative config: 512 wgs x 256 thr
#define TPB 256
#define RGRP 32            // row groups  (H / ROWS_PER_WG)
#define CGRP 16            // col groups  (H / COLS_PER_WG)
#define ROWS_PER_WG 128
#define COLS_PER_WG 256
#define NSLOT 10
#define NBUF 4             // partial ring: skew bound 2 (+1 write) < NBUF
#define TBLK 10            // t-blocking for Iin init
#define TAG_INVALID 0xFFFFFFFFu
#define DECAY_F 0.95122942450071400910f  // float(exp(-1/20))

// ---- workspace layout (bytes) ----
#define OFF_BAR   0                        // [0,8192): bwd stamps + barrier tree
#define OFF_IIN   8192                     // STEPS*H f32        = 1,638,400 B
#define OFF_PART  1646592                  // NBUF*RGRP*H u64    = 4,194,304 B
#define OFF_VSUM  5840896                  // H f32              =    16,384 B
#define OFF_RED   5857280                  // 64*64 f32          =    16,384 B
#define OFF_DLY8  5873664                  // H*H u8             = 16,777,216 B
#define WS_NEED_PACK 22650880

// word indices into bar[]
#define STAMP_BWD(c)  (512 + (c) * 32)     // [c][q]: reader q of col-group c's buf
#define BAR_GRP(g)    (1024 + (g) * 16)    // full-barrier tree: 16 groups of 32 wgs
#define BAR_GCNT      1280
#define BAR_FLAG      1296

#define ALOAD(p)      __hip_atomic_load((p),  __ATOMIC_RELAXED, __HIP_MEMORY_SCOPE_AGENT)
#define ASTORE(p,v)   __hip_atomic_store((p), (v), __ATOMIC_RELAXED, __HIP_MEMORY_SCOPE_AGENT)
#define ALOAD64(p)    __hip_atomic_load((p),  __ATOMIC_RELAXED, __HIP_MEMORY_SCOPE_AGENT)
#define ASTORE64(p,v) __hip_atomic_store((p), (v), __ATOMIC_RELAXED, __HIP_MEMORY_SCOPE_AGENT)

__device__ __forceinline__ void wait_ge(unsigned* p, unsigned tgt) {
    while (ALOAD(p) < tgt) __builtin_amdgcn_s_sleep(1);
}

// hierarchical full-grid barrier (monotonic generations) — init/readout only
__device__ __forceinline__ void full_barrier(unsigned* bar, int wg, unsigned gen, int tid) {
    __syncthreads();
    if (tid == 0) {
        __threadfence();                   // release (wbl2 — fine outside the loop)
        unsigned o = atomicAdd(bar + BAR_GRP(wg >> 5), 1u);
        if (o == gen * 32u - 1u) {
            unsigned g = atomicAdd(bar + BAR_GCNT, 1u);
            if (g == gen * 16u - 1u)
                ASTORE(bar + BAR_FLAG, gen);
        }
        wait_ge(bar + BAR_FLAG, gen);
        __threadfence();                   // acquire
    }
    __syncthreads();
}

__global__ __launch_bounds__(TPB, 2)
void triglial_kernel(const float* __restrict__ x,
                     const float* __restrict__ Wi,
                     const float* __restrict__ Wr,
                     const float* __restrict__ rw,
                     const float* __restrict__ rbias,
                     const int*   __restrict__ delays,
                     unsigned char* __restrict__ dly8,
                     int use_pack,
                     unsigned* __restrict__ bar,
                     float* __restrict__ Iin,
                     unsigned long long* __restrict__ partial,  // {tag,f32} words
                     float* __restrict__ vsum_g,
                     float* __restrict__ red_part,
                     float* __restrict__ out)
{
    const int wg   = blockIdx.x;
    const int tid  = threadIdx.x;
    const int rg   = wg >> 4;              // row-group id [0,32)
    const int cgi  = wg & 15;              // col-group id [0,16)
    const int rowbase = rg * ROWS_PER_WG;  // 128 presynaptic rows owned
    const int colbase = cgi * COLS_PER_WG; // 256 output cols owned
    const int wave = tid >> 6, lane = tid & 63;
    const int mycol = colbase + tid;       // exclusive column of this thread

    // LDS kept to the r4-r6 PROVEN envelope (~14.3 KB)
    __shared__ float s_acc[4][NSLOT][64];  // per-wave future-current accumulator
    __shared__ float s_part[2][ROWS_PER_WG];
    __shared__ float s_v[ROWS_PER_WG], s_rate[ROWS_PER_WG],
                     s_gamma[ROWS_PER_WG], s_vsum[ROWS_PER_WG];
    __shared__ unsigned long long s_spk[2];
    __shared__ float s_red[4][64];

    // ---------------- init ----------------
    if (tid < ROWS_PER_WG) {
        s_v[tid]=0.f; s_rate[tid]=0.f; s_gamma[tid]=1.f; s_vsum[tid]=0.f;
    }
    for (int i = tid; i < 4*NSLOT*64; i += TPB) ((float*)s_acc)[i] = 0.f;
    // partial ring: slot 0 = step 0 (tag 0, zero payload: empty delay buffer);
    // slots 1..3 tagged INVALID so consumers wait for the real exports.
    for (int idx = wg*TPB + tid; idx < NBUF*RGRP*H; idx += NWG*TPB) {
        const int slot = idx / (RGRP * H);
        const unsigned long long w =
            (slot == 0) ? 0ull : ((unsigned long long)TAG_INVALID << 32);
        ASTORE64(&partial[idx], w);
    }
    if (use_pack) {
        for (int idx = wg*TPB + tid; idx < H*H; idx += NWG*TPB)
            dly8[idx] = (unsigned char)(delays[idx] - 1);
    }
    // Iin[t][j] = x[t] . Wi[:,j] — t-blocked, NO LDS staging (x loads are
    // wave-uniform -> scalar-cached broadcasts). Wi read 10x total vs 100x.
    if (wg < (STEPS / TBLK) * CGRP) {      // 160 active wgs, one (10t x 256c) tile
        const int t0 = (wg / CGRP) * TBLK;
        const int j  = (wg % CGRP) * COLS_PER_WG + tid;
        float acc[TBLK];
        #pragma unroll
        for (int tt = 0; tt < TBLK; ++tt) acc[tt] = 0.f;
        for (int k = 0; k < IN_DIM_; ++k) {
            const float w = Wi[(size_t)k * H + j];
            #pragma unroll
            for (int tt = 0; tt < TBLK; ++tt)
                acc[tt] += x[(t0 + tt) * IN_DIM_ + k] * w;
        }
        #pragma unroll
        for (int tt = 0; tt < TBLK; ++tt) Iin[(t0 + tt) * H + j] = acc[tt];
    }
    full_barrier(bar, wg, 1u, tid);

    // ---- time loop: self-tagged dataflow, ZERO fences in the loop ----
    for (int t = 0; t < STEPS; ++t) {
        // bwd throttle: readers of my export buffer finished step t-3's reads
        // (protects this step's write of slot (t+1)&3). Fence-free: a reader's
        // load DATA was returned before its barrier released the bwd store.
        if (t >= 3 && tid < 32) {
            unsigned* addr = bar + STAMP_BWD(cgi) + lane;
            const unsigned tgt = (unsigned)(t - 2);
            int spins = 0;
            for (;;) {
                unsigned v = ALOAD(addr);
                if (__all((int)(v >= tgt))) break;
                if (((++spins) & 1023) == 0) __threadfence();  // stale-line rescue
                __builtin_amdgcn_s_sleep(2);
            }
        }
        __syncthreads();

        // ---- phase A: tagged reads of 32 partials per neuron (4-wide chunks) ----
        {
            const int n = tid & 127, p = tid >> 7;
            unsigned long long* pb = partial + (t & (NBUF-1)) * (RGRP * H);
            const int gn = rowbase + n;
            const unsigned want = (unsigned)t;
            float s = 0.f;
            #pragma unroll
            for (int c = 0; c < 4; ++c) {
                unsigned long long u[4];
                #pragma unroll
                for (int k = 0; k < 4; ++k)
                    u[k] = ALOAD64(&pb[(p*16 + c*4 + k) * H + gn]);
                int spins = 0;
                for (;;) {
                    bool stale = false;
                    #pragma unroll
                    for (int k = 0; k < 4; ++k) {
                        if ((unsigned)(u[k] >> 32) != want) {
                            stale = true;
                            u[k] = ALOAD64(&pb[(p*16 + c*4 + k) * H + gn]);
                        }
                    }
                    if (!stale) break;
                    if (((++spins) & 1023) == 0) __threadfence();
                    __builtin_amdgcn_s_sleep(1);
                }
                #pragma unroll
                for (int k = 0; k < 4; ++k) s += __uint_as_float((unsigned)u[k]);
            }
            s_part[p][n] = s;
        }
        __syncthreads();                   // phase-A data consumed into LDS
        if (tid == 0)                      // signal: my read of this buffer is done
            ASTORE(bar + STAMP_BWD(rg >> 1) + ((rg & 1) * 16 + cgi), (unsigned)(t + 1));

        // ---- LIF for this wg's 128 neurons (microglia mask==1: 0.99^99 > 0.01) ----
        if (tid < ROWS_PER_WG) {
            const float irec = s_part[0][tid] + s_part[1][tid];
            const float itot = (Iin[t*H + rowbase + tid] + irec) * s_gamma[tid];
            float v = s_v[tid] * DECAY_F + itot;
            const int spk = (v >= 1.0f) ? 1 : 0;
            v = spk ? 0.0f : v;
            s_v[tid] = v;
            s_vsum[tid] += v;              // reference records post-reset v
            const float rate = 0.9f * s_rate[tid] + 0.1f * (float)spk;
            s_rate[tid] = rate;
            float g = s_gamma[tid] + 0.01f * (0.1f - rate);
            s_gamma[tid] = fminf(fmaxf(g, 0.5f), 2.0f);
            const unsigned long long bal = __ballot(spk);
            if ((tid & 63) == 0) s_spk[tid >> 6] = bal;
        }
        __syncthreads();

        // ---- phase B: push spikes into future slots (16-deep load batching) ----
        if (t < STEPS - 1) {
            const int tmod = t % 10;
            unsigned long long m0 = s_spk[0], m1 = s_spk[1];
            while (m0 | m1) {
                float wv[16]; int dv[16];
                int cnt = 0;
                #pragma unroll
                for (int b = 0; b < 16; ++b) {
                    if (m0 | m1) {
                        int ii;
                        if (m0) { ii = __ffsll(m0) - 1; m0 &= m0 - 1; }
                        else    { ii = 64 + __ffsll(m1) - 1; m1 &= m1 - 1; }
                        const size_t base = (size_t)(rowbase + ii) * H + mycol;
                        wv[b] = Wr[base];                  // plain loads: L2-resident
                        dv[b] = use_pack ? (int)dly8[base] : (delays[base] - 1);
                        ++cnt;
                    }
                }
                #pragma unroll
                for (int b = 0; b < 16; ++b) {
                    if (b < cnt) {
                        int slot = tmod + 1 + dv[b];       // (t+1+d) mod 10
                        slot -= (slot >= 10) ? 10 : 0;
                        s_acc[wave][slot][lane] += wv[b];  // lane owns col: race-free
                    }
                }
            }
            int es = tmod + 1; es -= (es >= 10) ? 10 : 0;
            const float ex = s_acc[wave][es][lane];        // step-t+1 current complete
            s_acc[wave][es][lane] = 0.f;                   // recycle for t+11
            // self-tagged export: tag and payload in ONE atomic 8B word —
            // no cross-address ordering needed, ever.
            const unsigned long long w =
                ((unsigned long long)(unsigned)(t + 1) << 32)
                | (unsigned long long)__float_as_uint(ex);
            ASTORE64(&partial[((t+1) & (NBUF-1)) * (RGRP*H) + rg*H + mycol], w);
        }
        __syncthreads();
    }

    // ---------------- readout: out = (vsum/STEPS) @ rw + rbias ----------------
    if (cgi == 0 && tid < ROWS_PER_WG) vsum_g[rowbase + tid] = s_vsum[tid];
    full_barrier(bar, wg, 2u, tid);

    if (wg < 64) {                         // wg handles j in [wg*64, wg*64+64)
        const int o  = tid & 63;
        const int jl = tid >> 6;
        float s = 0.f;
        for (int j = wg*64 + jl; j < wg*64 + 64; j += 4)
            s += (vsum_g[j] * (1.0f / (float)STEPS)) * rw[j * OUT_DIM_ + o];
        s_red[jl][o] = s;
        __syncthreads();
        if (tid < 64)
            red_part[wg*64 + tid] =
                s_red[0][tid] + s_red[1][tid] + s_red[2][tid] + s_red[3][tid];
    }
    full_barrier(bar, wg, 3u, tid);

    if (wg == 0 && tid < OUT_DIM_) {
        float s = rbias[tid];
        #pragma unroll 8
        for (int w = 0; w < 64; ++w) s += red_part[w * 64 + tid];
        out[tid] = s;
    }
}

extern "C" void kernel_launch(void* const* d_in, const int* in_sizes, int n_in,
                              void* d_out, int out_size, void* d_ws, size_t ws_size,
                              hipStream_t stream) {
    const float* x      = (const float*)d_in[0];
    const float* Wi     = (const float*)d_in[1];
    const float* Wr     = (const float*)d_in[2];
    const float* rw     = (const float*)d_in[3];
    const float* rb     = (const float*)d_in[4];
    const int*   delays = (const int*)d_in[5];
    float* out = (float*)d_out;

    char* ws = (char*)d_ws;
    unsigned* bar   = (unsigned*)(ws + OFF_BAR);
    float* Iin      = (float*)(ws + OFF_IIN);
    unsigned long long* partial = (unsigned long long*)(ws + OFF_PART);
    float* vsum_g   = (float*)(ws + OFF_VSUM);
    float* red_part = (float*)(ws + OFF_RED);
    unsigned char* dly8 = (unsigned char*)(ws + OFF_DLY8);
    int use_pack = (ws_size >= (size_t)WS_NEED_PACK) ? 1 : 0;

    // zero bwd stamps + barrier tree (harness poisons ws with 0xAA each launch)
    hipMemsetAsync(ws + OFF_BAR, 0, 8192, stream);

    void* args[] = { (void*)&x, (void*)&Wi, (void*)&Wr, (void*)&rw, (void*)&rb,
                     (void*)&delays, (void*)&dly8, (void*)&use_pack, (void*)&bar,
                     (void*)&Iin, (void*)&partial, (void*)&vsum_g, (void*)&red_part,
                     (void*)&out };
    hipError_t err = hipLaunchCooperativeKernel((void*)triglial_kernel, dim3(NWG),
                                                dim3(TPB), args, 0, stream);
    if (err != hipSuccess) {
        // Fallback: plain launch. Kernel uses only hand-rolled sync; with
        // __launch_bounds__(256,2) and exactly 2 blocks/CU, all 512 blocks
        // are co-resident on the 256-CU device, so the spin protocol is safe.
        triglial_kernel<<<dim3(NWG), dim3(TPB), 0, stream>>>(
            x, Wi, Wr, rw, rb, delays, dly8, use_pack, bar,
            Iin, partial, vsum_g, red_part, out);
    }
}